// Round 1
// baseline (277.371 us; speedup 1.0000x reference)
//
#include <hip/hip_runtime.h>
#include <stdint.h>

// Problem constants (from reference: B=16,T=2048,D=256,K=8192)
#define NROWS 32768
#define DDIM  256
#define KCB   8192
#define BM    128          // rows per block
#define BN    64           // codebook entries per LDS tile
#define KHALF 4096         // each block handles half the codebook
#define ITERS (KHALF / BN) // 64

typedef __attribute__((ext_vector_type(8))) short short8; // 8 bf16 (4 VGPRs)
typedef __attribute__((ext_vector_type(4))) float f32x4;  // 4 fp32

__device__ __forceinline__ unsigned short f2bf(float f) {
  unsigned u = __builtin_bit_cast(unsigned, f);
  return (unsigned short)((u + 0x7FFFu + ((u >> 16) & 1u)) >> 16); // RNE
}

__device__ __forceinline__ void gload_lds16(const void* g, void* l) {
  __builtin_amdgcn_global_load_lds(
      (const __attribute__((address_space(1))) unsigned int*)g,
      (__attribute__((address_space(3))) unsigned int*)l, 16, 0, 0);
}

// ---------------- prep: embed fp32 -> bf16, half-squared-norms ----------------
__global__ void prep_embed(const float* __restrict__ embed,
                           unsigned short* __restrict__ ebf,
                           float* __restrict__ hesq) {
  const int t = threadIdx.x;
  const int lane = t & 63, w = t >> 6;
  const int row = blockIdx.x * 4 + w;
  const float4 v = *(const float4*)(embed + (size_t)row * DDIM + lane * 4);
  ushort4 b;
  b.x = f2bf(v.x); b.y = f2bf(v.y); b.z = f2bf(v.z); b.w = f2bf(v.w);
  *(ushort4*)(ebf + (size_t)row * DDIM + lane * 4) = b;
  float sq = v.x * v.x + v.y * v.y + v.z * v.z + v.w * v.w;
  #pragma unroll
  for (int m = 32; m; m >>= 1) sq += __shfl_xor(sq, m);
  if (lane == 0) hesq[row] = 0.5f * sq;
}

// ---------------- main: fused bf16 GEMM + per-row top-4 candidates ----------------
// score(row,col) = x.e - 0.5*|e|^2  (argmax-equivalent to reference)
// grid = 512: bid>>1 = M-tile (128 rows), bid&1 = K-half (4096 codes)
__launch_bounds__(256, 2)
__global__ void vq_main(const float* __restrict__ x,
                        const unsigned short* __restrict__ ebf,
                        const float* __restrict__ hesq,
                        int* __restrict__ cand) {
  __shared__ __align__(16) unsigned char sm[2 * 32768]; // double-buffered 64x512B tile
  const int t = threadIdx.x;
  const int lane = t & 63, w = t >> 6;
  const int lo = lane & 15, hi = lane >> 4;
  const int mtile = blockIdx.x >> 1, khalf = blockIdx.x & 1;
  const int mbase = mtile * BM;
  const int cbase0 = khalf * KHALF;
  const char* ebase = (const char*)ebf;

  // stage first tile into buf0 (pre-swizzled global source, linear LDS dest)
  #pragma unroll
  for (int i = 0; i < 8; ++i) {
    int gg = i * 256 + t;
    int c = gg >> 5, g = gg & 31;
    gload_lds16(ebase + ((size_t)(cbase0 + c) << 9) + ((size_t)((g ^ (c & 7)) << 4)),
                &sm[i * 4096 + w * 1024]);
  }

  // A fragments: 2 row-tiles x 8 k-chunks, resident whole kernel.
  // A[i][k]: i = lane&15, k = kk*32 + 8*(lane>>4) + e
  short8 af[2][8];
  #pragma unroll
  for (int rt = 0; rt < 2; ++rt) {
    const int row = mbase + w * 32 + rt * 16 + lo;
    const float* xr = x + (size_t)row * DDIM + hi * 8;
    #pragma unroll
    for (int kk = 0; kk < 8; ++kk) {
      float4 f0 = *(const float4*)(xr + kk * 32);
      float4 f1 = *(const float4*)(xr + kk * 32 + 4);
      short8 a;
      a[0] = (short)f2bf(f0.x); a[1] = (short)f2bf(f0.y);
      a[2] = (short)f2bf(f0.z); a[3] = (short)f2bf(f0.w);
      a[4] = (short)f2bf(f1.x); a[5] = (short)f2bf(f1.y);
      a[6] = (short)f2bf(f1.z); a[7] = (short)f2bf(f1.w);
      af[rt][kk] = a;
    }
  }

  float t1v[8], t2v[8];
  int   t1i[8], t2i[8];
  #pragma unroll
  for (int s = 0; s < 8; ++s) {
    t1v[s] = -__builtin_inff(); t2v[s] = -__builtin_inff();
    t1i[s] = 0; t2i[s] = 0;
  }

  __syncthreads(); // buf0 ready (syncthreads drains vmcnt)

  for (int it = 0; it < ITERS; ++it) {
    const int cb = cbase0 + it * BN;
    const unsigned char* buf = &sm[(it & 1) * 32768];

    if (it + 1 < ITERS) { // stage next tile
      unsigned char* nbuf = &sm[((it + 1) & 1) * 32768];
      #pragma unroll
      for (int i = 0; i < 8; ++i) {
        int gg = i * 256 + t;
        int c = gg >> 5, g = gg & 31;
        gload_lds16(ebase + ((size_t)(cb + BN + c) << 9) + ((size_t)((g ^ (c & 7)) << 4)),
                    nbuf + i * 4096 + w * 1024);
      }
    }

    float hq[4];
    #pragma unroll
    for (int st = 0; st < 4; ++st) hq[st] = hesq[cb + st * 16 + lo];

    f32x4 acc[2][4];
    #pragma unroll
    for (int rt = 0; rt < 2; ++rt)
      #pragma unroll
      for (int st = 0; st < 4; ++st)
        acc[rt][st] = (f32x4){0.f, 0.f, 0.f, 0.f};

    // B[k][j]: j = lane&15 (col in 16-subtile), k = kk*32 + 8*hi + e
    // LDS read swizzle matches staging involution: g_phys = g_log ^ (c&7)
    #pragma unroll
    for (int kk = 0; kk < 8; ++kk) {
      #pragma unroll
      for (int st = 0; st < 4; ++st) {
        const int c = st * 16 + lo;
        const int g = (kk * 4 + hi) ^ (c & 7);
        const short8 bf = *(const short8*)(buf + c * 512 + (g << 4));
        acc[0][st] = __builtin_amdgcn_mfma_f32_16x16x32_bf16(af[0][kk], bf, acc[0][st], 0, 0, 0);
        acc[1][st] = __builtin_amdgcn_mfma_f32_16x16x32_bf16(af[1][kk], bf, acc[1][st], 0, 0, 0);
      }
    }

    // epilogue: per-lane top-2 update. D[i][j]: i = 4*hi + r, j = lo
    #pragma unroll
    for (int rt = 0; rt < 2; ++rt) {
      #pragma unroll
      for (int st = 0; st < 4; ++st) {
        const int col = cb + st * 16 + lo;
        #pragma unroll
        for (int r = 0; r < 4; ++r) {
          const float s = acc[rt][st][r] - hq[st];
          const int sl = rt * 4 + r;
          const bool a = s > t1v[sl];
          const bool b = s > t2v[sl];
          t2v[sl] = a ? t1v[sl] : (b ? s : t2v[sl]);
          t2i[sl] = a ? t1i[sl] : (b ? col : t2i[sl]);
          t1v[sl] = a ? s : t1v[sl];
          t1i[sl] = a ? col : t1i[sl];
        }
      }
    }
    __syncthreads();
  }

  // merge per-lane top-2 across the 16 lanes sharing each row -> row top-4
  #pragma unroll
  for (int rt = 0; rt < 2; ++rt) {
    #pragma unroll
    for (int r = 0; r < 4; ++r) {
      const int sl = rt * 4 + r;
      float v0 = t1v[sl], v1 = t2v[sl], v2 = -__builtin_inff(), v3 = -__builtin_inff();
      int   i0 = t1i[sl], i1 = t2i[sl], i2 = 0, i3 = 0;
      #pragma unroll
      for (int m = 1; m <= 8; m <<= 1) {
        float w0 = __shfl_xor(v0, m), w1 = __shfl_xor(v1, m);
        float w2 = __shfl_xor(v2, m), w3 = __shfl_xor(v3, m);
        int   j0 = __shfl_xor(i0, m), j1 = __shfl_xor(i1, m);
        int   j2 = __shfl_xor(i2, m), j3 = __shfl_xor(i3, m);
        #define INS(bv, bi)                                                  \
        { bool g0 = bv > v0, g1 = bv > v1, g2 = bv > v2, g3 = bv > v3;       \
          float nv1 = g0 ? v0 : (g1 ? bv : v1); int ni1 = g0 ? i0 : (g1 ? bi : i1); \
          float nv2 = g1 ? v1 : (g2 ? bv : v2); int ni2 = g1 ? i1 : (g2 ? bi : i2); \
          float nv3 = g2 ? v2 : (g3 ? bv : v3); int ni3 = g2 ? i2 : (g3 ? bi : i3); \
          v0 = g0 ? bv : v0; i0 = g0 ? bi : i0;                              \
          v1 = nv1; i1 = ni1; v2 = nv2; i2 = ni2; v3 = nv3; i3 = ni3; }
        INS(w0, j0) INS(w1, j1) INS(w2, j2) INS(w3, j3)
        #undef INS
      }
      if (lo == 0) {
        const int row = mbase + w * 32 + rt * 16 + hi * 4 + r;
        int4 c4; c4.x = i0; c4.y = i1; c4.z = i2; c4.w = i3;
        *(int4*)(cand + (size_t)row * 8 + khalf * 4) = c4;
      }
    }
  }
}

// ---------------- rescore: exact distances for 8 candidates, gather output ----------------
__global__ void rescore_gather(const float* __restrict__ x,
                               const float* __restrict__ embed,
                               const int* __restrict__ cand,
                               float* __restrict__ out) {
  const int t = threadIdx.x;
  const int lane = t & 63, w = t >> 6;
  const int row = blockIdx.x * 4 + w;
  const float4 xv = *(const float4*)(x + (size_t)row * DDIM + lane * 4);
  double bd = 1e300;
  int bi = 0x7fffffff;
  #pragma unroll
  for (int c = 0; c < 8; ++c) {
    const int idx = cand[(size_t)row * 8 + c];
    const float4 ev = *(const float4*)(embed + (size_t)idx * DDIM + lane * 4);
    const float d0 = xv.x - ev.x, d1 = xv.y - ev.y;
    const float d2 = xv.z - ev.z, d3 = xv.w - ev.w;
    double d = (double)d0 * d0 + (double)d1 * d1 + (double)d2 * d2 + (double)d3 * d3;
    #pragma unroll
    for (int m = 32; m; m >>= 1) d += __shfl_xor(d, m);
    const bool better = (d < bd) || (d == bd && idx < bi); // tie -> lowest index
    bd = better ? d : bd;
    bi = better ? idx : bi;
  }
  const float4 ov = *(const float4*)(embed + (size_t)bi * DDIM + lane * 4);
  *(float4*)(out + (size_t)row * DDIM + lane * 4) = ov;
}

extern "C" void kernel_launch(void* const* d_in, const int* in_sizes, int n_in,
                              void* d_out, int out_size, void* d_ws, size_t ws_size,
                              hipStream_t stream) {
  const float* x     = (const float*)d_in[0];
  const float* embed = (const float*)d_in[1];
  float* out = (float*)d_out;

  char* wsb = (char*)d_ws;
  unsigned short* ebf = (unsigned short*)wsb;                            // 4 MB bf16 codebook
  float* hesq = (float*)(wsb + (size_t)KCB * DDIM * 2);                  // 32 KB
  int* cand   = (int*)(wsb + (size_t)KCB * DDIM * 2 + (size_t)KCB * 4);  // 1 MB candidates

  hipLaunchKernelGGL(prep_embed, dim3(KCB / 4), dim3(256), 0, stream, embed, ebf, hesq);
  hipLaunchKernelGGL(vq_main, dim3(512), dim3(256), 0, stream, x, ebf, hesq, cand);
  hipLaunchKernelGGL(rescore_gather, dim3(NROWS / 4), dim3(256), 0, stream, x, embed, cand, out);
}

// Round 4
// 277.244 us; speedup vs baseline: 1.0005x; 1.0005x over previous
//
#include <hip/hip_runtime.h>
#include <stdint.h>

// Problem constants (from reference: B=16,T=2048,D=256,K=8192)
#define NROWS 32768
#define DDIM  256
#define KCB   8192
#define BM    128          // rows per block
#define BN    32           // codebook entries per LDS tile
#define KQUART 2048        // each block handles a quarter of the codebook
#define ITERS (KQUART / BN) // 64

typedef __attribute__((ext_vector_type(8))) short short8; // 8 bf16 (4 VGPRs)
typedef __attribute__((ext_vector_type(4))) float f32x4;  // 4 fp32

__device__ __forceinline__ unsigned short f2bf(float f) {
  unsigned u = __builtin_bit_cast(unsigned, f);
  return (unsigned short)((u + 0x7FFFu + ((u >> 16) & 1u)) >> 16); // RNE
}

__device__ __forceinline__ void gload_lds16(const void* g, void* l) {
  __builtin_amdgcn_global_load_lds(
      (const __attribute__((address_space(1))) unsigned int*)g,
      (__attribute__((address_space(3))) unsigned int*)l, 16, 0, 0);
}

// ---------------- prep: embed fp32 -> bf16, NEGATED half-squared-norms ----------------
__global__ void prep_embed(const float* __restrict__ embed,
                           unsigned short* __restrict__ ebf,
                           float* __restrict__ nhesq) {
  const int t = threadIdx.x;
  const int lane = t & 63, w = t >> 6;
  const int row = blockIdx.x * 4 + w;
  const float4 v = *(const float4*)(embed + (size_t)row * DDIM + lane * 4);
  ushort4 b;
  b.x = f2bf(v.x); b.y = f2bf(v.y); b.z = f2bf(v.z); b.w = f2bf(v.w);
  *(ushort4*)(ebf + (size_t)row * DDIM + lane * 4) = b;
  float sq = v.x * v.x + v.y * v.y + v.z * v.z + v.w * v.w;
  #pragma unroll
  for (int m = 32; m; m >>= 1) sq += __shfl_xor(sq, m);
  if (lane == 0) nhesq[row] = -0.5f * sq;
}

// ---------------- main: fused bf16 GEMM + UNQUANTIZED top-2/slot screen ----------------
// score(row,col) = x.e - 0.5*|e|^2 (norm folded into MFMA C-init).
// Screen: full-precision float compares with separate index registers (R1-proven
// semantics). Values are stuffed with the 11-bit local index ONLY at output time,
// purely as an encoding for the rescore prefilter (selection is never quantized).
// grid = 1024: bid>>2 = M-tile (128 rows), bid&3 = K-quarter (2048 codes)
__launch_bounds__(256, 2)
__global__ void vq_main(const float* __restrict__ x,
                        const unsigned short* __restrict__ ebf,
                        const float* __restrict__ nhesq,
                        unsigned int* __restrict__ cand) {
  __shared__ __align__(16) unsigned char sm[2 * 16384]; // double-buffered 32x512B tile
  const int t = threadIdx.x;
  const int lane = t & 63, w = t >> 6;
  const int lo = lane & 15, hi = lane >> 4;
  const int mtile = blockIdx.x >> 2, q = blockIdx.x & 3;
  const int mbase = mtile * BM;
  const int qbase = q * KQUART;

  // --- staging: per-thread pre-swizzled global source, advances 16 KB/iter ---
  // logical column c = i*8 + (t>>5); 16B-chunk slot g = t&31, stored chunk = g ^ (c&7)
  const int sw = (((t & 31) ^ ((t >> 5) & 7)) << 4);
  const char* gsrc = (const char*)ebf + (size_t)qbase * 512 + (size_t)(t >> 5) * 512 + sw;

  #define STAGE(DSTOFF)                                                    \
    {                                                                      \
      _Pragma("unroll")                                                    \
      for (int i = 0; i < 4; ++i)                                          \
        gload_lds16(gsrc + i * 4096, &sm[(DSTOFF) + i * 4096 + w * 1024]); \
      gsrc += 16384;                                                       \
    }

  STAGE(0) // first tile into buf0

  // --- A fragments: 2 row-tiles x 8 k-chunks, resident whole kernel ---
  // A[i][k]: i = lane&15, k = kk*32 + 8*(lane>>4) + e
  short8 af[2][8];
  #pragma unroll
  for (int rt = 0; rt < 2; ++rt) {
    const int row = mbase + w * 32 + rt * 16 + lo;
    const float* xr = x + (size_t)row * DDIM + hi * 8;
    #pragma unroll
    for (int kk = 0; kk < 8; ++kk) {
      float4 f0 = *(const float4*)(xr + kk * 32);
      float4 f1 = *(const float4*)(xr + kk * 32 + 4);
      short8 a;
      a[0] = (short)f2bf(f0.x); a[1] = (short)f2bf(f0.y);
      a[2] = (short)f2bf(f0.z); a[3] = (short)f2bf(f0.w);
      a[4] = (short)f2bf(f1.x); a[5] = (short)f2bf(f1.y);
      a[6] = (short)f2bf(f1.z); a[7] = (short)f2bf(f1.w);
      af[rt][kk] = a;
    }
  }

  // --- iter-invariant LDS read addresses (swizzled) ---
  // read addr = raddr[kk] + st*8192 + bufoff; chunk slot = (kk*4+hi) ^ (lo&7)
  int raddr[8];
  #pragma unroll
  for (int kk = 0; kk < 8; ++kk)
    raddr[kk] = lo * 512 + ((((kk * 4 + hi) ^ (lo & 7))) << 4);

  // --- screen state: UNQUANTIZED top-2 + index per row-slot (class = 128 cols) ---
  const float NEGINF = __builtin_bit_cast(float, 0xFF800000u);
  float v1s[8], v2s[8];
  int   i1s[8], i2s[8];
  #pragma unroll
  for (int s = 0; s < 8; ++s) { v1s[s] = NEGINF; v2s[s] = NEGINF; i1s[s] = 0; i2s[s] = 0; }

  __syncthreads(); // buf0 ready (syncthreads drains vmcnt)

  #define BODY(BUFOFF, NEXTOFF, IT)                                              \
    {                                                                            \
      const int cbl = (IT) * BN; /* column base local to this quarter */         \
      if ((IT) + 1 < ITERS) STAGE(NEXTOFF)                                       \
      float nh[2];                                                               \
      _Pragma("unroll")                                                          \
      for (int st = 0; st < 2; ++st)                                             \
        nh[st] = nhesq[qbase + cbl + st * 16 + lo];                              \
      f32x4 acc[2][2];                                                           \
      _Pragma("unroll")                                                          \
      for (int rt = 0; rt < 2; ++rt)                                             \
        _Pragma("unroll")                                                        \
        for (int st = 0; st < 2; ++st)                                           \
          acc[rt][st] = (f32x4){nh[st], nh[st], nh[st], nh[st]};                 \
      _Pragma("unroll")                                                          \
      for (int kk = 0; kk < 8; ++kk) {                                           \
        _Pragma("unroll")                                                        \
        for (int st = 0; st < 2; ++st) {                                         \
          const short8 bf =                                                      \
              *(const short8*)(&sm[(BUFOFF) + st * 8192 + raddr[kk]]);           \
          acc[0][st] = __builtin_amdgcn_mfma_f32_16x16x32_bf16(af[0][kk], bf,    \
                                                               acc[0][st], 0, 0, 0); \
          acc[1][st] = __builtin_amdgcn_mfma_f32_16x16x32_bf16(af[1][kk], bf,    \
                                                               acc[1][st], 0, 0, 0); \
        }                                                                        \
      }                                                                          \
      const int col0 = cbl + lo, col1 = cbl + 16 + lo; /* local columns */       \
      _Pragma("unroll")                                                          \
      for (int rt = 0; rt < 2; ++rt)                                             \
        _Pragma("unroll")                                                        \
        for (int st = 0; st < 2; ++st) {                                         \
          const int col = st ? col1 : col0;                                      \
          _Pragma("unroll")                                                      \
          for (int r = 0; r < 4; ++r) {                                          \
            const float s = acc[rt][st][r];                                      \
            const int sl = rt * 4 + r;                                           \
            const bool a = s > v1s[sl];                                          \
            const bool b = s > v2s[sl];                                          \
            v2s[sl] = a ? v1s[sl] : (b ? s : v2s[sl]);                           \
            i2s[sl] = a ? i1s[sl] : (b ? col : i2s[sl]);                         \
            v1s[sl] = a ? s : v1s[sl];                                           \
            i1s[sl] = a ? col : i1s[sl];                                         \
          }                                                                      \
        }                                                                        \
      __syncthreads();                                                           \
    }

  for (int it2 = 0; it2 < ITERS; it2 += 2) {
    BODY(0, 16384, it2)
    BODY(16384, 0, it2 + 1)
  }
  #undef BODY
  #undef STAGE

  // --- merge per slot: cross-lane (16 lanes x top-2) -> top-4 with indices ---
  #define INS(bv, bi)                                                        \
  { const bool g0 = (bv) > v0, g1 = (bv) > v1, g2 = (bv) > v2, g3 = (bv) > v3; \
    const float nv1 = g0 ? v0 : (g1 ? (bv) : v1); const int ni1 = g0 ? i0 : (g1 ? (bi) : i1); \
    const float nv2 = g1 ? v1 : (g2 ? (bv) : v2); const int ni2 = g1 ? i1 : (g2 ? (bi) : i2); \
    const float nv3 = g2 ? v2 : (g3 ? (bv) : v3); const int ni3 = g2 ? i2 : (g3 ? (bi) : i3); \
    v0 = g0 ? (bv) : v0; i0 = g0 ? (bi) : i0;                                \
    v1 = nv1; i1 = ni1; v2 = nv2; i2 = ni2; v3 = nv3; i3 = ni3; }
  #pragma unroll
  for (int rt = 0; rt < 2; ++rt) {
    #pragma unroll
    for (int r = 0; r < 4; ++r) {
      const int sl = rt * 4 + r;
      float v0 = v1s[sl], v1 = v2s[sl], v2 = NEGINF, v3 = NEGINF;
      int   i0 = i1s[sl], i1 = i2s[sl], i2 = 0, i3 = 0;
      #pragma unroll
      for (int m = 1; m <= 8; m <<= 1) {
        const float w0 = __shfl_xor(v0, m), w1 = __shfl_xor(v1, m);
        const float w2 = __shfl_xor(v2, m), w3 = __shfl_xor(v3, m);
        const int   j0 = __shfl_xor(i0, m), j1 = __shfl_xor(i1, m);
        const int   j2 = __shfl_xor(i2, m), j3 = __shfl_xor(i3, m);
        INS(w0, j0) INS(w1, j1) INS(w2, j2) INS(w3, j3)
      }
      if (lo == 0) {
        const int row = mbase + w * 32 + rt * 16 + hi * 4 + r;
        // stuff 11-bit local index into low mantissa bits (encoding only --
        // all selection above used full-precision values)
        uint4 c4;
        c4.x = (__builtin_bit_cast(unsigned int, v0) & 0xFFFFF800u) | (unsigned int)i0;
        c4.y = (__builtin_bit_cast(unsigned int, v1) & 0xFFFFF800u) | (unsigned int)i1;
        c4.z = (__builtin_bit_cast(unsigned int, v2) & 0xFFFFF800u) | (unsigned int)i2;
        c4.w = (__builtin_bit_cast(unsigned int, v3) & 0xFFFFF800u) | (unsigned int)i3;
        *(uint4*)(cand + (size_t)row * 16 + q * 4) = c4;
      }
    }
  }
  #undef INS
}

// ---------------- rescore: prefiltered exact distances over 16 candidates ----------------
__global__ void rescore_gather(const float* __restrict__ x,
                               const float* __restrict__ embed,
                               const unsigned int* __restrict__ cand,
                               float* __restrict__ out) {
  const int t = threadIdx.x;
  const int lane = t & 63, w = t >> 6;
  const int row = blockIdx.x * 4 + w;

  uint4 cv[4];
  #pragma unroll
  for (int qq = 0; qq < 4; ++qq)
    cv[qq] = *(const uint4*)(cand + (size_t)row * 16 + qq * 4);
  unsigned int cw[16];
  #pragma unroll
  for (int qq = 0; qq < 4; ++qq) {
    cw[qq * 4 + 0] = cv[qq].x; cw[qq * 4 + 1] = cv[qq].y;
    cw[qq * 4 + 2] = cv[qq].z; cw[qq * 4 + 3] = cv[qq].w;
  }
  // NaN-safe max (NEGINF-stuffed padding decodes as NaN; fmaxf ignores it)
  float mx = -__builtin_inff();
  #pragma unroll
  for (int c = 0; c < 16; ++c) mx = fmaxf(mx, __builtin_bit_cast(float, cw[c]));
  // true-best bf16 screen value trails mx by <= 2x bf16 noise (~0.4) + stuff
  // quantization (~0.06); 1.0 is ample margin
  const float thr = mx - 1.0f;

  const float4 xv = *(const float4*)(x + (size_t)row * DDIM + lane * 4);
  double bd = 1e300;
  int bi = 0x7fffffff;
  float4 bv = {0.f, 0.f, 0.f, 0.f};
  #pragma unroll
  for (int c = 0; c < 16; ++c) {
    const float f = __builtin_bit_cast(float, cw[c]);
    if (f >= thr) { // wave-uniform branch (NaN compares false)
      const int idx = (int)(cw[c] & 0x7FFu) + (c >> 2) * KQUART;
      const float4 ev = *(const float4*)(embed + (size_t)idx * DDIM + lane * 4);
      const float d0 = xv.x - ev.x, d1 = xv.y - ev.y;
      const float d2 = xv.z - ev.z, d3 = xv.w - ev.w;
      double d = (double)d0 * d0 + (double)d1 * d1 + (double)d2 * d2 + (double)d3 * d3;
      #pragma unroll
      for (int m = 32; m; m >>= 1) d += __shfl_xor(d, m);
      const bool better = (d < bd) || (d == bd && idx < bi); // tie -> lowest index
      bd = better ? d : bd;
      bi = better ? idx : bi;
      bv.x = better ? ev.x : bv.x; bv.y = better ? ev.y : bv.y;
      bv.z = better ? ev.z : bv.z; bv.w = better ? ev.w : bv.w;
    }
  }
  *(float4*)(out + (size_t)row * DDIM + lane * 4) = bv;
}

extern "C" void kernel_launch(void* const* d_in, const int* in_sizes, int n_in,
                              void* d_out, int out_size, void* d_ws, size_t ws_size,
                              hipStream_t stream) {
  const float* x     = (const float*)d_in[0];
  const float* embed = (const float*)d_in[1];
  float* out = (float*)d_out;

  char* wsb = (char*)d_ws;
  unsigned short* ebf = (unsigned short*)wsb;                            // 4 MB bf16 codebook
  float* nhesq = (float*)(wsb + (size_t)KCB * DDIM * 2);                 // 32 KB
  unsigned int* cand =
      (unsigned int*)(wsb + (size_t)KCB * DDIM * 2 + (size_t)KCB * 4);   // 2 MB stuffed candidates

  hipLaunchKernelGGL(prep_embed, dim3(KCB / 4), dim3(256), 0, stream, embed, ebf, nhesq);
  hipLaunchKernelGGL(vq_main, dim3(1024), dim3(256), 0, stream, x, ebf, nhesq, cand);
  hipLaunchKernelGGL(rescore_gather, dim3(NROWS / 4), dim3(256), 0, stream, x, embed, cand, out);
}